// Round 1
// baseline (269.983 us; speedup 1.0000x reference)
//
#include <hip/hip_runtime.h>
#include <cstdint>
#include <cmath>

#define Bn 4096
#define Dn 256
#define On 256

typedef __bf16 v8bf __attribute__((ext_vector_type(8)));
typedef float  v4f  __attribute__((ext_vector_type(4)));

__device__ __forceinline__ unsigned short f2bf(float f) {
    // round-to-nearest-even fp32 -> bf16 (inputs are finite normals)
    unsigned int u = __builtin_bit_cast(unsigned int, f);
    unsigned int r = (u + 0x7fffu + ((u >> 16) & 1u)) >> 16;
    return (unsigned short)r;
}

__device__ __forceinline__ void gl_lds16(const void* g, void* l) {
    __builtin_amdgcn_global_load_lds(
        (const __attribute__((address_space(1))) void*)(uintptr_t)g,
        (__attribute__((address_space(3))) void*)(uintptr_t)l, 16, 0, 0);
}

// ---------------------------------------------------------------------------
// Kernel 1: build A[o] = triu(rots,1) + triu(rots,1)^T + diag(scales), as bf16.
// Grid: (16 tilepairs, O). 64x64 tiles, LDS transpose for the lower triangle.
// ---------------------------------------------------------------------------
__global__ __launch_bounds__(256) void build_A(
    const float* __restrict__ scales, const float* __restrict__ rots,
    unsigned short* __restrict__ Ab) {
    const int o  = blockIdx.y;
    const int ti = blockIdx.x >> 2, tj = blockIdx.x & 3;
    const int tid = threadIdx.x;
    const int si = (ti < tj) ? ti : tj;
    const int sj = (ti < tj) ? tj : ti;
    __shared__ float t[64][65];
    const float* src = rots + (size_t)o * Dn * Dn + (size_t)(si * 64) * Dn + sj * 64;
#pragma unroll
    for (int s = 0; s < 4; ++s) {
        const int l = s * 256 + tid;
        const int r = l >> 4, c = (l & 15) * 4;
        const float4 v = *(const float4*)(src + r * Dn + c);
        t[r][c] = v.x; t[r][c + 1] = v.y; t[r][c + 2] = v.z; t[r][c + 3] = v.w;
    }
    __syncthreads();
    unsigned short* dst = Ab + (size_t)o * Dn * Dn + (size_t)(ti * 64) * Dn + tj * 64;
#pragma unroll
    for (int s = 0; s < 4; ++s) {
        const int l = s * 256 + tid;
        const int r = l >> 4, c = (l & 15) * 4;
        float v[4];
        if (ti < tj) {            // strictly upper tile: copy
            v[0] = t[r][c]; v[1] = t[r][c + 1]; v[2] = t[r][c + 2]; v[3] = t[r][c + 3];
        } else if (ti > tj) {     // strictly lower tile: transpose of (tj,ti)
            v[0] = t[c][r]; v[1] = t[c + 1][r]; v[2] = t[c + 2][r]; v[3] = t[c + 3][r];
        } else {                  // diagonal tile
#pragma unroll
            for (int q = 0; q < 4; ++q) {
                const int jj = c + q;
                v[q] = (r < jj) ? t[r][jj]
                     : ((r > jj) ? t[jj][r] : scales[o * Dn + ti * 64 + r]);
            }
        }
        ushort4 u;
        u.x = f2bf(v[0]); u.y = f2bf(v[1]); u.z = f2bf(v[2]); u.w = f2bf(v[3]);
        *(ushort4*)(dst + r * Dn + c) = u;
    }
}

// ---------------------------------------------------------------------------
// Kernel 2: x fp32 -> bf16
// ---------------------------------------------------------------------------
__global__ __launch_bounds__(256) void cvt_x(const float* __restrict__ x,
                                             unsigned short* __restrict__ xb) {
    const int i = (blockIdx.x * 256 + threadIdx.x) * 4;
    const float4 v = *(const float4*)(x + i);
    ushort4 u;
    u.x = f2bf(v.x); u.y = f2bf(v.y); u.z = f2bf(v.z); u.w = f2bf(v.w);
    *(ushort4*)(xb + i) = u;
}

// ---------------------------------------------------------------------------
// Kernel 3: fused GEMM (y = A[o] x + c) + squared-norm + bell membership.
// Tile: 128 batch x 128 i per pass, 2 i-passes, BK=64, 4 waves.
// D output oriented [i x b]: row(m)=i, col(n)=b -> cheap norm reduction.
// XOR k-group swizzle in LDS slabs kills the stride-128B bank conflicts while
// keeping the global_load_lds lane-contiguous dest requirement (global side is
// a per-lane gather, so the permutation is applied to the SOURCE k-offset).
// ---------------------------------------------------------------------------
__global__ __launch_bounds__(256, 3) void fuzzy_main(
    const unsigned short* __restrict__ Ab, const unsigned short* __restrict__ xb,
    const float* __restrict__ cent, const float* __restrict__ bvals,
    float* __restrict__ out) {
    constexpr int BM = 128, BK = 64;
    __shared__ __align__(16) unsigned short Xs[BM * BK];
    __shared__ __align__(16) unsigned short As[BM * BK];
    __shared__ float ssbuf[2][BM];
    __shared__ float centL[Dn];

    const int tid  = threadIdx.x;
    const int lane = tid & 63;
    const int wv   = tid >> 6;
    const int b0   = blockIdx.x * BM;
    const int o    = blockIdx.y;

    ((float*)ssbuf)[tid] = 0.0f;          // 256 floats, all threads
    centL[tid] = cent[o * Dn + tid];      // stage centroids[o]

    const int wi = wv >> 1, wb = wv & 1;  // wave: i-quadrant, b-half
    const int frow = lane & 15, quad = lane >> 4;
    const int lr = lane >> 3, ls = lane & 7;
    const int ksw = (ls ^ lr) * 8;        // swizzled source k-offset (elements)
    const size_t Aoff = (size_t)o * Dn * Dn;

    for (int ip = 0; ip < 2; ++ip) {
        v4f acc[4][4];
#pragma unroll
        for (int mi = 0; mi < 4; ++mi)
#pragma unroll
            for (int ni = 0; ni < 4; ++ni)
                acc[mi][ni] = v4f{0.f, 0.f, 0.f, 0.f};

        for (int k0 = 0; k0 < Dn; k0 += BK) {
#pragma unroll
            for (int q = 0; q < 4; ++q) {
                const int reg = wv * 4 + q;       // 1KB region id, 0..15
                const int row = reg * 8 + lr;     // slab row, 0..127
                // LDS dest = slab_base + reg*1024 + lane*16 (wave-uniform + lane*16)
                gl_lds16(xb + (size_t)(b0 + row) * Dn + k0 + ksw,
                         &Xs[row * BK + ls * 8]);
                gl_lds16(Ab + Aoff + (size_t)(ip * BM + row) * Dn + k0 + ksw,
                         &As[row * BK + ls * 8]);
            }
            __syncthreads();   // drains vmcnt (global_load_lds) + lds
#pragma unroll
            for (int ks = 0; ks < 2; ++ks) {
                v8bf af[4], xf[4];
                const int slot = (ks * 4 + quad) ^ (frow & 7);
#pragma unroll
                for (int mi = 0; mi < 4; ++mi) {
                    const int r = wi * 64 + mi * 16 + frow;
                    af[mi] = *(const v8bf*)&As[r * BK + slot * 8];
                }
#pragma unroll
                for (int ni = 0; ni < 4; ++ni) {
                    const int r = wb * 64 + ni * 16 + frow;
                    xf[ni] = *(const v8bf*)&Xs[r * BK + slot * 8];
                }
#pragma unroll
                for (int mi = 0; mi < 4; ++mi)
#pragma unroll
                    for (int ni = 0; ni < 4; ++ni)
                        acc[mi][ni] = __builtin_amdgcn_mfma_f32_16x16x32_bf16(
                            af[mi], xf[ni], acc[mi][ni], 0, 0, 0);
            }
            __syncthreads();
        }
        // epilogue for this i-pass: y = acc + centroid; psum[ni] = sum_i y^2
        float psum[4] = {0.f, 0.f, 0.f, 0.f};
#pragma unroll
        for (int mi = 0; mi < 4; ++mi) {
            const int ib = ip * BM + wi * 64 + mi * 16 + quad * 4;
            const float c0 = centL[ib], c1 = centL[ib + 1];
            const float c2 = centL[ib + 2], c3 = centL[ib + 3];
#pragma unroll
            for (int ni = 0; ni < 4; ++ni) {
                const float y0 = acc[mi][ni][0] + c0;
                const float y1 = acc[mi][ni][1] + c1;
                const float y2 = acc[mi][ni][2] + c2;
                const float y3 = acc[mi][ni][3] + c3;
                psum[ni] += y0 * y0 + y1 * y1 + y2 * y2 + y3 * y3;
            }
        }
#pragma unroll
        for (int ni = 0; ni < 4; ++ni) {
            float v = psum[ni];
            v += __shfl_xor(v, 16);   // combine the 4 quads (same b, different i)
            v += __shfl_xor(v, 32);
            if (lane < 16) ssbuf[wi][wb * 64 + ni * 16 + lane] += v;
        }
    }
    __syncthreads();
    if (tid < BM) {
        const float ssq = ssbuf[0][tid] + ssbuf[1][tid];  // rx^2
        // rx^(2b) = (rx^2)^b
        out[(size_t)(b0 + tid) * On + o] = 1.0f / (1.0f + powf(ssq, bvals[o]));
    }
}

// ---------------------------------------------------------------------------
// Fallback (only if d_ws is too small): exact fp32, slow but correct.
// ---------------------------------------------------------------------------
__global__ void fallback_kernel(const float* __restrict__ x, const float* __restrict__ scales,
                                const float* __restrict__ rots, const float* __restrict__ cent,
                                const float* __restrict__ bvals, float* __restrict__ out) {
    const int b = blockIdx.x * blockDim.x + threadIdx.x;
    const int o = blockIdx.y;
    if (b >= Bn) return;
    const float* R  = rots + (size_t)o * Dn * Dn;
    const float* xv = x + (size_t)b * Dn;
    float ss = 0.f;
    for (int i = 0; i < Dn; ++i) {
        float a = cent[o * Dn + i];
        for (int j = 0; j < Dn; ++j) {
            const float w = (j > i) ? R[i * Dn + j]
                          : ((j < i) ? R[j * Dn + i] : scales[o * Dn + i]);
            a += w * xv[j];
        }
        ss += a * a;
    }
    out[(size_t)b * On + o] = 1.f / (1.f + powf(ss, bvals[o]));
}

extern "C" void kernel_launch(void* const* d_in, const int* in_sizes, int n_in,
                              void* d_out, int out_size, void* d_ws, size_t ws_size,
                              hipStream_t stream) {
    const float* x         = (const float*)d_in[0];
    const float* scales    = (const float*)d_in[1];
    const float* rots      = (const float*)d_in[2];
    const float* centroids = (const float*)d_in[3];
    const float* bvals     = (const float*)d_in[4];
    float* out = (float*)d_out;

    const size_t needA = (size_t)On * Dn * Dn * sizeof(unsigned short); // 33.5 MB
    const size_t needX = (size_t)Bn * Dn * sizeof(unsigned short);      //  2.1 MB

    if (ws_size >= needA + needX) {
        unsigned short* Ab = (unsigned short*)d_ws;
        unsigned short* xb = (unsigned short*)((char*)d_ws + needA);
        build_A<<<dim3(16, On), 256, 0, stream>>>(scales, rots, Ab);
        cvt_x<<<dim3((Bn * Dn) / 1024), 256, 0, stream>>>(x, xb);
        fuzzy_main<<<dim3(Bn / 128, On), 256, 0, stream>>>(Ab, xb, centroids, bvals, out);
    } else {
        fallback_kernel<<<dim3(Bn / 256, On), 256, 0, stream>>>(x, scales, rots, centroids,
                                                                bvals, out);
    }
}

// Round 2
// 251.457 us; speedup vs baseline: 1.0737x; 1.0737x over previous
//
#include <hip/hip_runtime.h>
#include <cstdint>
#include <cmath>

#define Bn 4096
#define Dn 256
#define On 256

typedef __bf16 v8bf __attribute__((ext_vector_type(8)));
typedef float  v4f  __attribute__((ext_vector_type(4)));
typedef unsigned short us8 __attribute__((ext_vector_type(8)));

__device__ __forceinline__ unsigned short f2bf(float f) {
    // round-to-nearest-even fp32 -> bf16 (inputs are finite normals)
    unsigned int u = __builtin_bit_cast(unsigned int, f);
    unsigned int r = (u + 0x7fffu + ((u >> 16) & 1u)) >> 16;
    return (unsigned short)r;
}

__device__ __forceinline__ void gl_lds16(const void* g, void* l) {
    __builtin_amdgcn_global_load_lds(
        (const __attribute__((address_space(1))) void*)(uintptr_t)g,
        (__attribute__((address_space(3))) void*)(uintptr_t)l, 16, 0, 0);
}

// ---------------------------------------------------------------------------
// Kernel 1: build A[o] = triu(rots,1) + triu(rots,1)^T + diag(scales), bf16.
// One block per UNORDERED 64x64 tile pair (10 pairs per o): each mirror source
// tile is read ONCE (42 MB total vs 67), stores are 16B/lane. Off-diag pairs
// write the direct tile straight from registers and the mirror via LDS
// transpose; diagonal pairs do the triu/mirror/scales select from LDS.
// ---------------------------------------------------------------------------
__global__ __launch_bounds__(256) void build_A(
    const float* __restrict__ scales, const float* __restrict__ rots,
    unsigned short* __restrict__ Ab) {
    static const int TI[10] = {0, 0, 0, 0, 1, 1, 1, 2, 2, 3};
    static const int TJ[10] = {0, 1, 2, 3, 1, 2, 3, 2, 3, 3};
    const int o  = blockIdx.y;
    const int ti = TI[blockIdx.x], tj = TJ[blockIdx.x];
    const int tid = threadIdx.x;
    const int r = tid >> 3;          // 0..31
    const int c = (tid & 7) * 8;     // 0..56, 8-float segment

    __shared__ float t[64][65];
    const float* src = rots + (size_t)o * Dn * Dn + (size_t)(ti * 64) * Dn + tj * 64;
    unsigned short* dstU = Ab + (size_t)o * Dn * Dn + (size_t)(ti * 64) * Dn + tj * 64;
    unsigned short* dstL = Ab + (size_t)o * Dn * Dn + (size_t)(tj * 64) * Dn + ti * 64;

    float f[2][8];
#pragma unroll
    for (int s = 0; s < 2; ++s) {
        const int rr = s * 32 + r;
        const float4 v0 = *(const float4*)(src + rr * Dn + c);
        const float4 v1 = *(const float4*)(src + rr * Dn + c + 4);
        f[s][0] = v0.x; f[s][1] = v0.y; f[s][2] = v0.z; f[s][3] = v0.w;
        f[s][4] = v1.x; f[s][5] = v1.y; f[s][6] = v1.z; f[s][7] = v1.w;
#pragma unroll
        for (int q = 0; q < 8; ++q) t[rr][c + q] = f[s][q];
    }
    __syncthreads();

    if (ti != tj) {
#pragma unroll
        for (int s = 0; s < 2; ++s) {       // direct (upper) tile from registers
            const int rr = s * 32 + r;
            us8 u;
#pragma unroll
            for (int q = 0; q < 8; ++q) u[q] = f2bf(f[s][q]);
            *(us8*)(dstU + rr * Dn + c) = u;
        }
#pragma unroll
        for (int s = 0; s < 2; ++s) {       // mirror tile = transpose via LDS
            const int rr = s * 32 + r;
            us8 u;
#pragma unroll
            for (int q = 0; q < 8; ++q) u[q] = f2bf(t[c + q][rr]);
            *(us8*)(dstL + rr * Dn + c) = u;
        }
    } else {
#pragma unroll
        for (int s = 0; s < 2; ++s) {       // diagonal tile
            const int rr = s * 32 + r;
            us8 u;
#pragma unroll
            for (int q = 0; q < 8; ++q) {
                const int jj = c + q;
                const float v = (rr < jj) ? t[rr][jj]
                              : ((rr > jj) ? t[jj][rr]
                                           : scales[o * Dn + ti * 64 + rr]);
                u[q] = f2bf(v);
            }
            *(us8*)(dstU + rr * Dn + c) = u;
        }
    }
}

// ---------------------------------------------------------------------------
// Kernel 2: x fp32 -> bf16
// ---------------------------------------------------------------------------
__global__ __launch_bounds__(256) void cvt_x(const float* __restrict__ x,
                                             unsigned short* __restrict__ xb) {
    const int i = (blockIdx.x * 256 + threadIdx.x) * 4;
    const float4 v = *(const float4*)(x + i);
    ushort4 u;
    u.x = f2bf(v.x); u.y = f2bf(v.y); u.z = f2bf(v.z); u.w = f2bf(v.w);
    *(ushort4*)(xb + i) = u;
}

// ---------------------------------------------------------------------------
// Kernel 3: fused GEMM (y = A[o] x + c) + squared-norm + bell membership.
// MERGED single pass: 128 batch x 256 i, BK=64, 4 waves; wave wv owns i-rows
// [wv*64, wv*64+64) x all 128 b. acc[4][8] (128 VGPR), 64 MFMA/wave between
// barrier pairs (2x round 1), X tile staged once (25% fewer staging bytes),
// 8 barriers total (vs 16). XOR k-group swizzle unchanged (conflict-free,
// verified 0 conflicts in round 1). Output written COALESCED to outT[o][b]
// (round 1 wrote a 128x1 column of out -> 119 MB write amplification).
// ---------------------------------------------------------------------------
__global__ __launch_bounds__(256, 2) void fuzzy_main(
    const unsigned short* __restrict__ Ab, const unsigned short* __restrict__ xb,
    const float* __restrict__ cent, const float* __restrict__ bvals,
    float* __restrict__ obase, int sb, int so) {
    constexpr int BK = 64;
    __shared__ __align__(16) unsigned short Xs[128 * BK];   // 16 KB
    __shared__ __align__(16) unsigned short As[256 * BK];   // 32 KB
    __shared__ float ssbuf[4][128];
    __shared__ float centL[Dn];

    const int tid  = threadIdx.x;
    const int lane = tid & 63;
    const int wv   = tid >> 6;
    const int b0   = blockIdx.x * 128;
    const int o    = blockIdx.y;

    centL[tid] = cent[o * Dn + tid];

    const int frow = lane & 15, quad = lane >> 4;
    const int lr = lane >> 3, ls = lane & 7;
    const int ksw = (ls ^ lr) * 8;        // swizzled source k-offset (elements)
    const size_t Aoff = (size_t)o * Dn * Dn;

    v4f acc[4][8];
#pragma unroll
    for (int mi = 0; mi < 4; ++mi)
#pragma unroll
        for (int ni = 0; ni < 8; ++ni)
            acc[mi][ni] = v4f{0.f, 0.f, 0.f, 0.f};

    for (int k0 = 0; k0 < Dn; k0 += BK) {
#pragma unroll
        for (int q = 0; q < 4; ++q) {     // Xs: 16 x 1KB regions, 4 per wave
            const int row = (wv * 4 + q) * 8 + lr;
            gl_lds16(xb + (size_t)(b0 + row) * Dn + k0 + ksw,
                     &Xs[row * BK + ls * 8]);
        }
#pragma unroll
        for (int q = 0; q < 8; ++q) {     // As: 32 x 1KB regions, 8 per wave
            const int row = (wv * 8 + q) * 8 + lr;
            gl_lds16(Ab + Aoff + (size_t)row * Dn + k0 + ksw,
                     &As[row * BK + ls * 8]);
        }
        __syncthreads();
#pragma unroll
        for (int ks = 0; ks < 2; ++ks) {
            const int slot = (ks * 4 + quad) ^ (frow & 7);
            v8bf af[4], xf[8];
#pragma unroll
            for (int mi = 0; mi < 4; ++mi) {
                const int rr = wv * 64 + mi * 16 + frow;
                af[mi] = *(const v8bf*)&As[rr * BK + slot * 8];
            }
#pragma unroll
            for (int ni = 0; ni < 8; ++ni) {
                const int rr = ni * 16 + frow;
                xf[ni] = *(const v8bf*)&Xs[rr * BK + slot * 8];
            }
#pragma unroll
            for (int mi = 0; mi < 4; ++mi)
#pragma unroll
                for (int ni = 0; ni < 8; ++ni)
                    acc[mi][ni] = __builtin_amdgcn_mfma_f32_16x16x32_bf16(
                        af[mi], xf[ni], acc[mi][ni], 0, 0, 0);
        }
        __syncthreads();
    }

    // epilogue: y = acc + centroid; reduce sum_i y^2 across i
    float cv[4][4];
#pragma unroll
    for (int mi = 0; mi < 4; ++mi)
#pragma unroll
        for (int rg = 0; rg < 4; ++rg)
            cv[mi][rg] = centL[wv * 64 + mi * 16 + quad * 4 + rg];
#pragma unroll
    for (int ni = 0; ni < 8; ++ni) {
        float v = 0.f;
#pragma unroll
        for (int mi = 0; mi < 4; ++mi)
#pragma unroll
            for (int rg = 0; rg < 4; ++rg) {
                const float y = acc[mi][ni][rg] + cv[mi][rg];
                v += y * y;
            }
        v += __shfl_xor(v, 16);           // combine 4 quads (same b col)
        v += __shfl_xor(v, 32);
        if (lane < 16) ssbuf[wv][ni * 16 + lane] = v;
    }
    __syncthreads();
    if (tid < 128) {
        const float ssq = ssbuf[0][tid] + ssbuf[1][tid] + ssbuf[2][tid] + ssbuf[3][tid];
        obase[(size_t)(b0 + tid) * sb + (size_t)o * so] =
            1.0f / (1.0f + powf(ssq, bvals[o]));
    }
}

// ---------------------------------------------------------------------------
// Kernel 4: transpose outT [O][B] -> out [B][O] (both coalesced, 64x64 tiles)
// ---------------------------------------------------------------------------
__global__ __launch_bounds__(256) void transp(const float* __restrict__ outT,
                                              float* __restrict__ out) {
    __shared__ float t[64][65];
    const int bb = blockIdx.x * 64;
    const int ob = blockIdx.y * 64;
    const int tid = threadIdx.x;
    const int r = tid >> 4;          // 0..15
    const int c = (tid & 15) * 4;
#pragma unroll
    for (int s = 0; s < 4; ++s) {
        const int rr = s * 16 + r;   // o index within tile
        const float4 v = *(const float4*)(outT + (size_t)(ob + rr) * Bn + bb + c);
        t[rr][c] = v.x; t[rr][c + 1] = v.y; t[rr][c + 2] = v.z; t[rr][c + 3] = v.w;
    }
    __syncthreads();
#pragma unroll
    for (int s = 0; s < 4; ++s) {
        const int rr = s * 16 + r;   // b index within tile
        float4 w;
        w.x = t[c][rr]; w.y = t[c + 1][rr]; w.z = t[c + 2][rr]; w.w = t[c + 3][rr];
        *(float4*)(out + (size_t)(bb + rr) * On + ob + c) = w;
    }
}

// ---------------------------------------------------------------------------
// Fallback (only if d_ws is too small): exact fp32, slow but correct.
// ---------------------------------------------------------------------------
__global__ void fallback_kernel(const float* __restrict__ x, const float* __restrict__ scales,
                                const float* __restrict__ rots, const float* __restrict__ cent,
                                const float* __restrict__ bvals, float* __restrict__ out) {
    const int b = blockIdx.x * blockDim.x + threadIdx.x;
    const int o = blockIdx.y;
    if (b >= Bn) return;
    const float* R  = rots + (size_t)o * Dn * Dn;
    const float* xv = x + (size_t)b * Dn;
    float ss = 0.f;
    for (int i = 0; i < Dn; ++i) {
        float a = cent[o * Dn + i];
        for (int j = 0; j < Dn; ++j) {
            const float w = (j > i) ? R[i * Dn + j]
                          : ((j < i) ? R[j * Dn + i] : scales[o * Dn + i]);
            a += w * xv[j];
        }
        ss += a * a;
    }
    out[(size_t)b * On + o] = 1.f / (1.f + powf(ss, bvals[o]));
}

extern "C" void kernel_launch(void* const* d_in, const int* in_sizes, int n_in,
                              void* d_out, int out_size, void* d_ws, size_t ws_size,
                              hipStream_t stream) {
    const float* x         = (const float*)d_in[0];
    const float* scales    = (const float*)d_in[1];
    const float* rots      = (const float*)d_in[2];
    const float* centroids = (const float*)d_in[3];
    const float* bvals     = (const float*)d_in[4];
    float* out = (float*)d_out;

    const size_t needA = (size_t)On * Dn * Dn * sizeof(unsigned short); // 33.5 MB
    const size_t needX = (size_t)Bn * Dn * sizeof(unsigned short);      //  2.1 MB
    const size_t needT = (size_t)On * Bn * sizeof(float);               //  4.2 MB

    if (ws_size >= needA + needX) {
        unsigned short* Ab = (unsigned short*)d_ws;
        unsigned short* xb = (unsigned short*)((char*)d_ws + needA);
        build_A<<<dim3(10, On), 256, 0, stream>>>(scales, rots, Ab);
        cvt_x<<<dim3((Bn * Dn) / 1024), 256, 0, stream>>>(x, xb);
        if (ws_size >= needA + needX + needT) {
            float* outT = (float*)((char*)d_ws + needA + needX);
            fuzzy_main<<<dim3(Bn / 128, On), 256, 0, stream>>>(Ab, xb, centroids, bvals,
                                                               outT, 1, Bn);
            transp<<<dim3(Bn / 64, On / 64), 256, 0, stream>>>(outT, out);
        } else {
            fuzzy_main<<<dim3(Bn / 128, On), 256, 0, stream>>>(Ab, xb, centroids, bvals,
                                                               out, On, 1);
        }
    } else {
        fallback_kernel<<<dim3(Bn / 256, On), 256, 0, stream>>>(x, scales, rots, centroids,
                                                                bvals, out);
    }
}